// Round 1
// baseline (815.165 us; speedup 1.0000x reference)
//
#include <hip/hip_runtime.h>
#include <cstdint>
#include <cmath>

#define NB 64
#define NS 2048
#define NR 1024
#define NH 512
#define SC 32              // s-chunks in weighted-sum kernel
#define SCHUNK (NS / SC)   // 64

__device__ __forceinline__ float waveReduceSum(float v) {
    #pragma unroll
    for (int off = 32; off > 0; off >>= 1) v += __shfl_down(v, off, 64);
    return v;
}

__device__ __forceinline__ float fast_tanh(float x) {
    // tanh(x) = (e^{2x}-1)/(e^{2x}+1); clamp so exp never overflows.
    float cx = fminf(fmaxf(x, -15.f), 15.f);
    float e = __expf(2.f * cx);
    return __fdividef(e - 1.f, e + 1.f);
}

// ---------------- Kernel 1: att_h[b,o] = sum_k h[b,k]*W[o,k] + bias[o] ----------------
__global__ __launch_bounds__(256) void k_atth(
    const float* __restrict__ h, const float* __restrict__ W,
    const float* __restrict__ bias, float* __restrict__ att_h)
{
    const int o = blockIdx.x;  // 0..NH-1
    __shared__ float wsh[NR];
    for (int i = threadIdx.x; i < NR; i += 256) wsh[i] = W[(size_t)o * NR + i];
    __syncthreads();
    const int wave = threadIdx.x >> 6, lane = threadIdx.x & 63;
    const float4* w4 = (const float4*)wsh;
    const float bo = bias[o];
    for (int b = wave; b < NB; b += 4) {
        const float4* h4 = (const float4*)(h + (size_t)b * NR);
        float acc = 0.f;
        #pragma unroll
        for (int i = 0; i < NR / 4 / 64; ++i) {  // 4 iters
            float4 a = h4[lane + i * 64];
            float4 w = w4[lane + i * 64];
            acc += a.x * w.x + a.y * w.y + a.z * w.z + a.w * w.w;
        }
        acc = waveReduceSum(acc);
        if (lane == 0) att_h[b * NH + o] = acc + bo;
    }
}

// ---------------- Kernel 2: scores[b,s] (skip masked rows entirely) ----------------
__global__ __launch_bounds__(256) void k_scores(
    const float* __restrict__ p, const float* __restrict__ att_h,
    const float* __restrict__ w_alpha, const float* __restrict__ b_alpha,
    const int* __restrict__ masks, float* __restrict__ scores)
{
    const int b = blockIdx.x >> 9;                         // NS/4 = 512 blocks per b
    const int s = ((blockIdx.x & 511) << 2) + (threadIdx.x >> 6);
    const int lane = threadIdx.x & 63;
    __shared__ float ah[NH], wa[NH];
    for (int i = threadIdx.x; i < NH; i += 256) {
        ah[i] = att_h[b * NH + i];
        wa[i] = w_alpha[i];
    }
    __syncthreads();
    const int sidx = b * NS + s;
    if (masks[sidx] == 0) {          // wave-uniform: whole wave skips, p row never read
        if (lane == 0) scores[sidx] = -INFINITY;
        return;
    }
    const float4* p4  = (const float4*)(p + (size_t)sidx * NH);
    const float4* ah4 = (const float4*)ah;
    const float4* wa4 = (const float4*)wa;
    float acc = 0.f;
    #pragma unroll
    for (int i = 0; i < 2; ++i) {
        float4 x = p4[lane + i * 64];
        float4 a = ah4[lane + i * 64];
        float4 w = wa4[lane + i * 64];
        acc += fast_tanh(x.x + a.x) * w.x;
        acc += fast_tanh(x.y + a.y) * w.y;
        acc += fast_tanh(x.z + a.z) * w.z;
        acc += fast_tanh(x.w + a.w) * w.w;
    }
    acc = waveReduceSum(acc);
    if (lane == 0) scores[sidx] = acc + b_alpha[0];
}

// ---------------- Kernel 3: masked softmax per batch ----------------
// weight[b,s] = exp(score - max) / sum  (masked entries have score=-inf -> weight 0)
__global__ __launch_bounds__(1024) void k_softmax(
    const float* __restrict__ scores, float* __restrict__ weights)
{
    const int b = blockIdx.x;
    const int tid = threadIdx.x;
    __shared__ float red[16];
    float s0 = scores[b * NS + tid];
    float s1 = scores[b * NS + tid + 1024];
    float m = fmaxf(s0, s1);
    #pragma unroll
    for (int off = 32; off > 0; off >>= 1) m = fmaxf(m, __shfl_down(m, off, 64));
    if ((tid & 63) == 0) red[tid >> 6] = m;
    __syncthreads();
    float M = red[0];
    #pragma unroll
    for (int i = 1; i < 16; ++i) M = fmaxf(M, red[i]);
    __syncthreads();   // everyone done reading red before it's reused
    float e0 = __expf(s0 - M);   // exp(-inf) = 0 for masked
    float e1 = __expf(s1 - M);
    float t = e0 + e1;
    t = waveReduceSum(t);
    if ((tid & 63) == 0) red[tid >> 6] = t;
    __syncthreads();
    float T = 0.f;
    #pragma unroll
    for (int i = 0; i < 16; ++i) T += red[i];
    const float invT = 1.0f / T;
    weights[b * NS + tid]        = e0 * invT;
    weights[b * NS + tid + 1024] = e1 * invT;
}

// ---------------- Kernel 4: att_res[b,r] = sum_s weight[b,s] * att_feats[b,s,r] -------
__global__ __launch_bounds__(256) void k_wsum(
    const float* __restrict__ feats, const float* __restrict__ weights,
    float* __restrict__ out)
{
    const int b  = blockIdx.x >> 5;   // SC = 32
    const int sc = blockIdx.x & 31;
    const int s0 = sc * SCHUNK;
    __shared__ float wsh[SCHUNK];
    if (threadIdx.x < SCHUNK) wsh[threadIdx.x] = weights[b * NS + s0 + threadIdx.x];
    __syncthreads();
    const float4* f4 = (const float4*)(feats + ((size_t)b * NS + s0) * NR);
    float4 acc = make_float4(0.f, 0.f, 0.f, 0.f);
    for (int s = 0; s < SCHUNK; ++s) {
        float w = wsh[s];
        if (w != 0.f) {               // wave-uniform skip: masked rows never fetched
            float4 v = f4[(size_t)s * 256 + threadIdx.x];
            acc.x += w * v.x; acc.y += w * v.y; acc.z += w * v.z; acc.w += w * v.w;
        }
    }
    float* o = out + b * NR + threadIdx.x * 4;
    atomicAdd(o + 0, acc.x);
    atomicAdd(o + 1, acc.y);
    atomicAdd(o + 2, acc.z);
    atomicAdd(o + 3, acc.w);
}

extern "C" void kernel_launch(void* const* d_in, const int* in_sizes, int n_in,
                              void* d_out, int out_size, void* d_ws, size_t ws_size,
                              hipStream_t stream) {
    const float* h        = (const float*)d_in[0];
    const float* feats    = (const float*)d_in[1];
    const float* p        = (const float*)d_in[2];
    const int*   masks    = (const int*)d_in[3];
    const float* W        = (const float*)d_in[4];
    const float* bh       = (const float*)d_in[5];
    const float* w_alpha  = (const float*)d_in[6];
    const float* b_alpha  = (const float*)d_in[7];
    float* out = (float*)d_out;

    float* ws      = (float*)d_ws;
    float* att_h   = ws;                         // NB*NH   = 32768 floats
    float* scores  = att_h + NB * NH;            // NB*NS   = 131072 floats
    float* weights = scores + NB * NS;           // NB*NS   = 131072 floats

    hipMemsetAsync(d_out, 0, (size_t)out_size * sizeof(float), stream);

    k_atth<<<NH, 256, 0, stream>>>(h, W, bh, att_h);
    k_scores<<<NB * (NS / 4), 256, 0, stream>>>(p, att_h, w_alpha, b_alpha, masks, scores);
    k_softmax<<<NB, 1024, 0, stream>>>(scores, weights);
    k_wsum<<<NB * SC, 256, 0, stream>>>(feats, weights, out);
}